// Round 1
// baseline (1180.815 us; speedup 1.0000x reference)
//
#include <hip/hip_runtime.h>
#include <hip/hip_bf16.h>

typedef __attribute__((ext_vector_type(8))) short short8;
typedef __attribute__((ext_vector_type(4))) float f32x4;

#define NB 8
#define NT 1024
#define NC 512
#define NHID 2048
#define NK 31
#define NH 4
#define NTP 994            // NT - NK + 1
#define MROWS (NB * NTP)   // 7952

__device__ __forceinline__ void gload_lds16(const void* g, void* l) {
  __builtin_amdgcn_global_load_lds(
      (const __attribute__((address_space(1))) void*)g,
      (__attribute__((address_space(3))) void*)l, 16, 0, 0);
}

// ---------------------------------------------------------------------------
// prep_wc: Wc (O=2048, C=512, K=31) fp32 -> Wt[k][cb][o][ci] bf16
// block handles (o-tile of 8, cb of 64 channels, all 31 k). grid = 256*8 = 2048
// ---------------------------------------------------------------------------
__global__ __launch_bounds__(256) void prep_wc(const float* __restrict__ Wc,
                                               __hip_bfloat16* __restrict__ Wt) {
  const int blk = blockIdx.x;
  const int cb = blk & 7;
  const int o0 = (blk >> 3) << 3;  // 8 o's per block
  const int c0 = cb << 6;
  __shared__ float lds[8 * 64 * NK];  // [ol][cl][k]  63.5KB
  for (int ol = 0; ol < 8; ++ol) {
    const float* src = Wc + ((size_t)(o0 + ol) * NC + c0) * NK;
    for (int i = threadIdx.x; i < 64 * NK; i += 256) lds[ol * (64 * NK) + i] = src[i];
  }
  __syncthreads();
  // out element (k, ol, ci) -> Wt[((k*8+cb)*2048 + o0+ol)*64 + ci]
  for (int i = threadIdx.x; i < NK * 8 * 64; i += 256) {
    const int k = i >> 9;          // /512
    const int rem = i & 511;
    const int ol = rem >> 6;
    const int ci = rem & 63;
    Wt[((size_t)(k * 8 + cb) * NHID + o0 + ol) * 64 + ci] =
        __float2bfloat16(lds[ol * (64 * NK) + ci * NK + k]);
  }
}

// ---------------------------------------------------------------------------
// prep_w2: W2 (C=512, HID=2048) fp32 -> W2t[ob][c][oi] bf16  (ob=o/64, oi=o%64)
// ---------------------------------------------------------------------------
__global__ __launch_bounds__(256) void prep_w2(const float* __restrict__ W2,
                                               __hip_bfloat16* __restrict__ W2t) {
  const int i = blockIdx.x * 256 + threadIdx.x;  // over 32*512*64 = 1048576
  if (i < 32 * 512 * 64) {
    const int oi = i & 63;
    const int c = (i >> 6) & 511;
    const int ob = i >> 15;
    W2t[i] = __float2bfloat16(W2[(size_t)c * NHID + (ob << 6) + oi]);
  }
}

// ---------------------------------------------------------------------------
// dynconv: per (b,t) block -> y[b,t,c] = sum_j softmax_w[h,j]*x[b,t+j-15,c] + bias[c]
// stored bf16 (B,T,C)
// ---------------------------------------------------------------------------
__global__ __launch_bounds__(256) void dynconv(const float* __restrict__ x,
                                               const float* __restrict__ Wl,
                                               const float* __restrict__ bl,
                                               const float* __restrict__ bias,
                                               __hip_bfloat16* __restrict__ Y) {
  const int t = blockIdx.x;
  const int b = blockIdx.y;
  const int tid = threadIdx.x;
  __shared__ float xt[NC];
  __shared__ float lg[NH * NK];
  __shared__ float wsm[NH][NK];

  const float* xrow = x + ((size_t)b * NT + t) * NC;
  for (int c = tid; c < NC; c += 256) xt[c] = xrow[c];
  __syncthreads();

  if (tid < NH * NK) {
    const float* wrow = Wl + (size_t)tid * NC;
    float s = 0.f;
#pragma unroll 8
    for (int c = 0; c < NC; ++c) s += xt[c] * wrow[c];
    lg[tid] = s + bl[tid];
  }
  __syncthreads();

  if (tid < NH) {
    int jlo = 15 - t; if (jlo < 0) jlo = 0;
    int jhi = 1038 - t; if (jhi > 30) jhi = 30;
    float mx = -1e30f;
    for (int j = jlo; j <= jhi; ++j) mx = fmaxf(mx, lg[tid * NK + j]);
    float ssum = 0.f;
    for (int j = 0; j < NK; ++j) {
      float e = (j >= jlo && j <= jhi) ? expf(lg[tid * NK + j] - mx) : 0.f;
      wsm[tid][j] = e;
      ssum += e;
    }
    const float inv = 1.f / ssum;
    for (int j = 0; j < NK; ++j) wsm[tid][j] *= inv;
  }
  __syncthreads();

  for (int c = tid; c < NC; c += 256) {
    const int h = c >> 7;
    float acc = 0.f;
#pragma unroll
    for (int j = 0; j < NK; ++j) {
      const int pos = t + j - 15;
      if (pos >= 0 && pos < NT) acc += wsm[h][j] * x[((size_t)b * NT + pos) * NC + c];
    }
    Y[((size_t)b * NT + t) * NC + c] = __float2bfloat16(acc + bias[c]);
  }
}

// ---------------------------------------------------------------------------
// conv_gemm: z[(b,t'),o] = sum_{k,c} Y[b,t'+k,c] * Wc[o,c,k]; + bc; selu -> Z bf16
// 128x128 tile, 4 waves (2x2 of 64x64), BK=64, K-loop over 31 k * 8 cb = 248
// ---------------------------------------------------------------------------
__global__ __launch_bounds__(256) void conv_gemm(const __hip_bfloat16* __restrict__ Y,
                                                 const __hip_bfloat16* __restrict__ Wt,
                                                 const float* __restrict__ bc,
                                                 __hip_bfloat16* __restrict__ Z) {
  const int o0 = blockIdx.x << 7;
  const int t0 = blockIdx.y << 7;
  const int b = blockIdx.z;
  __shared__ __align__(16) __hip_bfloat16 As[128 * 64];
  __shared__ __align__(16) __hip_bfloat16 Bs[128 * 64];
  const int tid = threadIdx.x;
  const int lane = tid & 63, wid = tid >> 6;
  const int wr = wid >> 1, wc = wid & 1;

  f32x4 acc[4][4] = {};

  for (int k = 0; k < NK; ++k) {
    for (int cb = 0; cb < 8; ++cb) {
      const int c0 = cb << 6;
      // stage A: Y rows t0+row+k, cols c0..c0+63 -> As[row][ci]
#pragma unroll
      for (int r = 0; r < 4; ++r) {
        const int chunk = (r << 2) | wid;
        const int row = (chunk << 3) + (lane >> 3);
        int trow = t0 + row + k;
        if (trow > NT - 1) trow = NT - 1;  // rows past t'=993 are garbage, unused
        const __hip_bfloat16* src =
            Y + (((size_t)b * NT + trow) << 9) + c0 + ((lane & 7) << 3);
        gload_lds16(src, &As[chunk << 9]);
      }
      // stage B: contiguous 16KB chunk of Wt
      const __hip_bfloat16* wb = Wt + ((size_t)((k << 3) | cb) * NHID + o0) * 64;
#pragma unroll
      for (int r = 0; r < 4; ++r) {
        const int chunk = (r << 2) | wid;
        gload_lds16(wb + (chunk << 9) + (lane << 3), &Bs[chunk << 9]);
      }
      __syncthreads();
#pragma unroll
      for (int kk = 0; kk < 2; ++kk) {
        const int ko = (kk << 5) + ((lane >> 4) << 3);
        short8 av[4], bv[4];
#pragma unroll
        for (int m = 0; m < 4; ++m)
          av[m] = *(const short8*)&As[(((wr << 6) + (m << 4) + (lane & 15)) << 6) + ko];
#pragma unroll
        for (int n = 0; n < 4; ++n)
          bv[n] = *(const short8*)&Bs[(((wc << 6) + (n << 4) + (lane & 15)) << 6) + ko];
#pragma unroll
        for (int m = 0; m < 4; ++m)
#pragma unroll
          for (int n = 0; n < 4; ++n)
            acc[m][n] = __builtin_amdgcn_mfma_f32_16x16x32_bf16(av[m], bv[n], acc[m][n], 0, 0, 0);
      }
      __syncthreads();
    }
  }

  const float kS = 1.0507009873554805f;
  const float kAS = 1.7580993408473766f;  // scale*alpha
#pragma unroll
  for (int n = 0; n < 4; ++n) {
    const int col = o0 + (wc << 6) + (n << 4) + (lane & 15);
    const float bcv = bc[col];
#pragma unroll
    for (int m = 0; m < 4; ++m) {
      const int rbase = (wr << 6) + (m << 4) + ((lane >> 4) << 2);
#pragma unroll
      for (int r = 0; r < 4; ++r) {
        const int tp = t0 + rbase + r;
        if (tp < NTP) {
          const float v = acc[m][n][r] + bcv;
          const float s = v > 0.f ? kS * v : kAS * (__expf(v) - 1.f);
          Z[((size_t)b * NTP + tp) * NHID + col] = __float2bfloat16(s);
        }
      }
    }
  }
}

// ---------------------------------------------------------------------------
// out_gemm: Out[row, c] = sum_o Z[row, o] * W2[c, o] + b2[c]   (fp32 out)
// M = 7952 rows, N = 512, K = 2048
// ---------------------------------------------------------------------------
__global__ __launch_bounds__(256) void out_gemm(const __hip_bfloat16* __restrict__ Zm,
                                                const __hip_bfloat16* __restrict__ W2t,
                                                const float* __restrict__ b2,
                                                float* __restrict__ Out) {
  const int n0 = blockIdx.x << 7;
  const int m0 = blockIdx.y << 7;
  __shared__ __align__(16) __hip_bfloat16 As[128 * 64];
  __shared__ __align__(16) __hip_bfloat16 Bs[128 * 64];
  const int tid = threadIdx.x;
  const int lane = tid & 63, wid = tid >> 6;
  const int wr = wid >> 1, wc = wid & 1;

  f32x4 acc[4][4] = {};

  for (int kb = 0; kb < 32; ++kb) {
#pragma unroll
    for (int r = 0; r < 4; ++r) {
      const int chunk = (r << 2) | wid;
      int row = m0 + (chunk << 3) + (lane >> 3);
      if (row > MROWS - 1) row = MROWS - 1;
      gload_lds16(Zm + ((size_t)row << 11) + (kb << 6) + ((lane & 7) << 3),
                  &As[chunk << 9]);
    }
    const __hip_bfloat16* wb = W2t + ((size_t)(kb * NC + n0) << 6);
#pragma unroll
    for (int r = 0; r < 4; ++r) {
      const int chunk = (r << 2) | wid;
      gload_lds16(wb + (chunk << 9) + (lane << 3), &Bs[chunk << 9]);
    }
    __syncthreads();
#pragma unroll
    for (int kk = 0; kk < 2; ++kk) {
      const int ko = (kk << 5) + ((lane >> 4) << 3);
      short8 av[4], bv[4];
#pragma unroll
      for (int m = 0; m < 4; ++m)
        av[m] = *(const short8*)&As[(((wr << 6) + (m << 4) + (lane & 15)) << 6) + ko];
#pragma unroll
      for (int n = 0; n < 4; ++n)
        bv[n] = *(const short8*)&Bs[(((wc << 6) + (n << 4) + (lane & 15)) << 6) + ko];
#pragma unroll
      for (int m = 0; m < 4; ++m)
#pragma unroll
        for (int n = 0; n < 4; ++n)
          acc[m][n] = __builtin_amdgcn_mfma_f32_16x16x32_bf16(av[m], bv[n], acc[m][n], 0, 0, 0);
    }
    __syncthreads();
  }

#pragma unroll
  for (int n = 0; n < 4; ++n) {
    const int col = n0 + (wc << 6) + (n << 4) + (lane & 15);
    const float b2v = b2[col];
#pragma unroll
    for (int m = 0; m < 4; ++m) {
      const int rbase = m0 + (wr << 6) + (m << 4) + ((lane >> 4) << 2);
#pragma unroll
      for (int r = 0; r < 4; ++r) {
        const int row = rbase + r;
        if (row < MROWS) Out[(size_t)row * NC + col] = acc[m][n][r] + b2v;
      }
    }
  }
}

// ---------------------------------------------------------------------------
extern "C" void kernel_launch(void* const* d_in, const int* in_sizes, int n_in,
                              void* d_out, int out_size, void* d_ws, size_t ws_size,
                              hipStream_t stream) {
  const float* x = (const float*)d_in[0];
  const float* Wl = (const float*)d_in[1];
  const float* bl = (const float*)d_in[2];
  const float* bias = (const float*)d_in[3];
  const float* Wc = (const float*)d_in[4];
  const float* bc = (const float*)d_in[5];
  const float* W2 = (const float*)d_in[6];
  const float* b2 = (const float*)d_in[7];
  float* out = (float*)d_out;

  char* ws = (char*)d_ws;
  __hip_bfloat16* Wt = (__hip_bfloat16*)(ws);                    // 31*8*2048*64*2 = 65,011,712
  __hip_bfloat16* Y = (__hip_bfloat16*)(ws + 65011712);          // 8*1024*512*2   =  8,388,608
  __hip_bfloat16* W2t = (__hip_bfloat16*)(ws + 73400320);        // 32*512*64*2    =  2,097,152
  __hip_bfloat16* Z = (__hip_bfloat16*)(ws + 75497472);          // 8*994*2048*2   = 32,571,392

  hipLaunchKernelGGL(prep_wc, dim3(2048), dim3(256), 0, stream, Wc, Wt);
  hipLaunchKernelGGL(prep_w2, dim3(4096), dim3(256), 0, stream, W2, W2t);
  hipLaunchKernelGGL(dynconv, dim3(NT, NB), dim3(256), 0, stream, x, Wl, bl, bias, Y);
  hipLaunchKernelGGL(conv_gemm, dim3(NHID / 128, 8, NB), dim3(256), 0, stream, Y, Wt, bc, Z);
  hipLaunchKernelGGL(out_gemm, dim3(NC / 128, (MROWS + 127) / 128), dim3(256), 0, stream,
                     Z, W2t, b2, out);
}

// Round 3
// 757.822 us; speedup vs baseline: 1.5582x; 1.5582x over previous
//
#include <hip/hip_runtime.h>
#include <hip/hip_bf16.h>

typedef __attribute__((ext_vector_type(8))) short short8;
typedef __attribute__((ext_vector_type(4))) float f32x4;

#define NB 8
#define NT 1024
#define NC 512
#define NHID 2048
#define NK 31
#define NH 4
#define NTP 994            // NT - NK + 1
#define MROWS (NB * NTP)   // 7952
#define TG 4               // t's per dynconv block

__device__ __forceinline__ void gload_lds16(const void* g, void* l) {
  __builtin_amdgcn_global_load_lds(
      (const __attribute__((address_space(1))) void*)g,
      (__attribute__((address_space(3))) void*)l, 16, 0, 0);
}

// ---------------------------------------------------------------------------
// prep_wc: Wc (O=2048, C=512, K=31) fp32 -> Wt tiles [ob][cb][k][or][ci']
//   tile = 128 o-rows x 64 ci, ci' = ci ^ ((or&7)<<3)  (T2 swizzle baked in)
//   flat index: ((ob*8 + cb)*31 + k)*8192 + or*64 + ci'
// block: (o-tile of 8 rows, cb of 64 channels, all 31 k). grid = 2048
// ---------------------------------------------------------------------------
__global__ __launch_bounds__(256) void prep_wc(const float* __restrict__ Wc,
                                               __hip_bfloat16* __restrict__ Wt) {
  const int blk = blockIdx.x;
  const int cb = blk & 7;
  const int o0 = (blk >> 3) << 3;  // 8 o's per block
  const int c0 = cb << 6;
  const int ob = o0 >> 7;
  const int orb = o0 & 127;        // row base within 128-tile (mult of 8)
  __shared__ float lds[8 * 64 * NK];  // [ol][cl][k]  63.5KB
  for (int ol = 0; ol < 8; ++ol) {
    const float* src = Wc + ((size_t)(o0 + ol) * NC + c0) * NK;
    for (int i = threadIdx.x; i < 64 * NK; i += 256) lds[ol * (64 * NK) + i] = src[i];
  }
  __syncthreads();
  for (int i = threadIdx.x; i < NK * 8 * 64; i += 256) {
    const int k = i >> 9;          // /512
    const int rem = i & 511;
    const int ol = rem >> 6;
    const int ci = rem & 63;
    Wt[((size_t)((ob * 8 + cb) * NK + k) << 13) + ((orb + ol) << 6) + (ci ^ (ol << 3))] =
        __float2bfloat16(lds[ol * (64 * NK) + ci * NK + k]);
  }
}

// ---------------------------------------------------------------------------
// prep_w2: W2 (C=512, HID=2048) fp32 -> W2t tiles [nb][kb][cr][oi']
//   tile = 128 c-rows x 64 oi, oi' = oi ^ ((cr&7)<<3)
//   flat: ((nb*32 + kb)*128 + (c&127))*64 + oi'
// ---------------------------------------------------------------------------
__global__ __launch_bounds__(256) void prep_w2(const float* __restrict__ W2,
                                               __hip_bfloat16* __restrict__ W2t) {
  const int i = blockIdx.x * 256 + threadIdx.x;  // over 32*512*64 = 1048576
  if (i < 32 * 512 * 64) {
    const int oi = i & 63;
    const int c = (i >> 6) & 511;
    const int kb = i >> 15;
    const size_t dst = ((size_t)(((c >> 7) * 32 + kb) * 128 + (c & 127)) << 6) +
                       (oi ^ ((c & 7) << 3));
    W2t[dst] = __float2bfloat16(W2[(size_t)c * NHID + (kb << 6) + oi]);
  }
}

// ---------------------------------------------------------------------------
// dynconv: 4 t's per block. y[b,t,c] = sum_j w[h,j]*x[b,t+j-15,c] + bias[c]
// Y stored bf16 (B,T,C) with per-row swizzle: within each 64-ch block,
//   c' = c ^ ((t&7)<<3)   (so conv_gemm's LDS copy is conflict-free)
// ---------------------------------------------------------------------------
__global__ __launch_bounds__(256) void dynconv(const float* __restrict__ x,
                                               const float* __restrict__ Wl,
                                               const float* __restrict__ bl,
                                               const float* __restrict__ bias,
                                               __hip_bfloat16* __restrict__ Y) {
  const int t0 = blockIdx.x * TG;
  const int b = blockIdx.y;
  const int tid = threadIdx.x, lane = tid & 63, w = tid >> 6;
  __shared__ float xt[TG][NC];
  __shared__ float lg[TG][NH * NK];
  __shared__ float wsm[TG][NH][NK];

  for (int i = tid; i < TG * NC; i += 256) {
    const int tg = i >> 9, c = i & 511;
    xt[tg][c] = x[((size_t)b * NT + t0 + tg) * NC + c];
  }
  __syncthreads();

  // logits: wave w handles ids w, w+4, ... (124 = 4 waves * 31)
  for (int i = 0; i < 31; ++i) {
    const int id = (i << 2) | w;  // 0..123
    const float* wrow = Wl + (size_t)id * NC + (lane << 3);
    float wv[8];
#pragma unroll
    for (int u = 0; u < 8; ++u) wv[u] = wrow[u];
    const float blv = bl[id];
#pragma unroll
    for (int tg = 0; tg < TG; ++tg) {
      float s = 0.f;
#pragma unroll
      for (int u = 0; u < 8; ++u) s += xt[tg][(lane << 3) + u] * wv[u];
#pragma unroll
      for (int off = 32; off; off >>= 1) s += __shfl_xor(s, off);
      if (lane == 0) lg[tg][id] = s + blv;
    }
  }
  __syncthreads();

  if (tid < TG * NH) {  // 16 threads: (tg,h)
    const int tg = tid >> 2, h = tid & 3;
    const int t = t0 + tg;
    int jlo = 15 - t; if (jlo < 0) jlo = 0;
    int jhi = 1038 - t; if (jhi > 30) jhi = 30;
    float mx = -1e30f;
    for (int j = jlo; j <= jhi; ++j) mx = fmaxf(mx, lg[tg][h * NK + j]);
    float ssum = 0.f;
    for (int j = 0; j < NK; ++j) {
      const float e = (j >= jlo && j <= jhi) ? __expf(lg[tg][h * NK + j] - mx) : 0.f;
      wsm[tg][h][j] = e;
      ssum += e;
    }
    const float inv = 1.f / ssum;
    for (int j = 0; j < NK; ++j) wsm[tg][h][j] *= inv;
  }
  __syncthreads();

  // gather: thread owns float2 channel pair (c = 2*tid, 2*tid+1)
  const int c = tid << 1;
  const int h = c >> 7;
  const float2* x2 = (const float2*)x;
  const float bias0 = bias[c], bias1 = bias[c + 1];
#pragma unroll
  for (int tg = 0; tg < TG; ++tg) {
    const int t = t0 + tg;
    float a0 = 0.f, a1 = 0.f;
#pragma unroll
    for (int j = 0; j < NK; ++j) {
      int pos = t + j - 15;
      pos = pos < 0 ? 0 : (pos > NT - 1 ? NT - 1 : pos);  // OOB taps have w==0
      const float wgt = wsm[tg][h][j];
      const float2 v = x2[(((size_t)b * NT + pos) << 8) + tid];
      a0 += wgt * v.x;
      a1 += wgt * v.y;
    }
    const int cs = (c & ~63) | ((c & 63) ^ ((t & 7) << 3));  // swizzled (bit0 preserved)
    __hip_bfloat162 hv;
    hv.x = __float2bfloat16(a0 + bias0);
    hv.y = __float2bfloat16(a1 + bias1);
    *(__hip_bfloat162*)(Y + ((size_t)b * NT + t) * NC + cs) = hv;
  }
}

// ---------------------------------------------------------------------------
// conv_gemm: z[(b,t'),o] = sum_{k,c} Y[b,t'+k,c]*Wc[o,c,k]; +bc; selu -> Z bf16
// 128x128 tile, 4 waves (2x2). Per cb: stage Ys[160][64] once, slide k.
// B double-buffered + prefetch. All LDS reads XOR-swizzled (conflict-free).
// Z written swizzled with key = FLATTENED row (b*NTP+tp)&7 -- must match
// out_gemm's read key, since NTP % 8 != 0 (R2 bug: used tp&7).
// ---------------------------------------------------------------------------
__global__ __launch_bounds__(256) void conv_gemm(const __hip_bfloat16* __restrict__ Y,
                                                 const __hip_bfloat16* __restrict__ Wt,
                                                 const float* __restrict__ bc,
                                                 __hip_bfloat16* __restrict__ Z) {
  const int o0 = blockIdx.x << 7;
  const int t0 = blockIdx.y << 7;
  const int b = blockIdx.z;
  __shared__ __align__(16) __hip_bfloat16 Ys[160 * 64];      // 20 KB
  __shared__ __align__(16) __hip_bfloat16 Bs[2][128 * 64];   // 2x16 KB
  const int tid = threadIdx.x;
  const int lane = tid & 63, wid = tid >> 6;
  const int wr = wid >> 1, wc = wid & 1;
  const int obase = (o0 >> 7) * 8;

  f32x4 acc[4][4] = {};

  auto stageY = [&](int cb_) {
    const int c0 = cb_ << 6;
#pragma unroll
    for (int p = 0; p < 5; ++p) {
      const int i = (p << 8) + tid;         // 1280 chunks of 16B = 160 rows
      int grow = t0 + (i >> 3);
      if (grow > NT - 1) grow = NT - 1;     // feeds only discarded output rows
      gload_lds16(Y + (((size_t)b * NT + grow) << 9) + c0 + ((i & 7) << 3),
                  &Ys[i << 3]);
    }
  };
  auto stageB = [&](int bufi, int cb_, int k_) {
    const __hip_bfloat16* wb = Wt + (((size_t)(obase + cb_) * NK + k_) << 13);
#pragma unroll
    for (int p = 0; p < 4; ++p) {
      const int i = (p << 8) + tid;         // 1024 chunks of 16B
      gload_lds16(wb + (i << 3), &Bs[bufi][i << 3]);
    }
  };

  int buf = 0;
  stageY(0);
  stageB(0, 0, 0);
  __syncthreads();

  for (int cb = 0; cb < 8; ++cb) {
    for (int k = 0; k < NK; ++k) {
      if (k < NK - 1) stageB(buf ^ 1, cb, k + 1);  // prefetch overlaps MFMA
#pragma unroll
      for (int kk = 0; kk < 2; ++kk) {
        const int ko = (kk << 5) + ((lane >> 4) << 3);
        short8 av[4], bv[4];
#pragma unroll
        for (int m = 0; m < 4; ++m) {
          const int r2 = (wr << 6) + (m << 4) + (lane & 15) + k;
          av[m] = *(const short8*)&Ys[(r2 << 6) + (ko ^ ((r2 & 7) << 3))];
        }
#pragma unroll
        for (int n = 0; n < 4; ++n) {
          const int br = (wc << 6) + (n << 4) + (lane & 15);
          bv[n] = *(const short8*)&Bs[buf][(br << 6) + (ko ^ ((br & 7) << 3))];
        }
#pragma unroll
        for (int m = 0; m < 4; ++m)
#pragma unroll
          for (int n = 0; n < 4; ++n)
            acc[m][n] = __builtin_amdgcn_mfma_f32_16x16x32_bf16(av[m], bv[n], acc[m][n], 0, 0, 0);
      }
      __syncthreads();
      buf ^= 1;
    }
    if (cb < 7) {  // boundary: refill Ys + first B of next cb (small bubble, 7x)
      stageY(cb + 1);
      stageB(buf, cb + 1, 0);
      __syncthreads();
    }
  }

  const float kS = 1.0507009873554805f;
  const float kAS = 1.7580993408473766f;  // scale*alpha
#pragma unroll
  for (int n = 0; n < 4; ++n) {
    const int col = o0 + (wc << 6) + (n << 4) + (lane & 15);
    const float bcv = bc[col];
#pragma unroll
    for (int m = 0; m < 4; ++m) {
      const int rbase = (wr << 6) + (m << 4) + ((lane >> 4) << 2);
#pragma unroll
      for (int r = 0; r < 4; ++r) {
        const int tp = t0 + rbase + r;
        if (tp < NTP) {
          const float v = acc[m][n][r] + bcv;
          const float s = v > 0.f ? kS * v : kAS * (__expf(v) - 1.f);
          const size_t grow = (size_t)b * NTP + tp;   // flattened row
          const int cs = (col & ~63) | ((col & 63) ^ (((int)(grow & 7)) << 3));
          Z[grow * NHID + cs] = __float2bfloat16(s);
        }
      }
    }
  }
}

// ---------------------------------------------------------------------------
// out_gemm: Out[row,c] = sum_o Z[row,o]*W2[c,o] + b2[c]  (fp32), M=7952,N=512,K=2048
// Z and W2t are pre-swizzled (Z key = flattened row&7); reads XOR-swizzled.
// ---------------------------------------------------------------------------
__global__ __launch_bounds__(256) void out_gemm(const __hip_bfloat16* __restrict__ Zm,
                                                const __hip_bfloat16* __restrict__ W2t,
                                                const float* __restrict__ b2,
                                                float* __restrict__ Out) {
  const int n0 = blockIdx.x << 7;
  const int m0 = blockIdx.y << 7;
  __shared__ __align__(16) __hip_bfloat16 As[128 * 64];
  __shared__ __align__(16) __hip_bfloat16 Bs[128 * 64];
  const int tid = threadIdx.x;
  const int lane = tid & 63, wid = tid >> 6;
  const int wr = wid >> 1, wc = wid & 1;

  f32x4 acc[4][4] = {};

  for (int kb = 0; kb < 32; ++kb) {
#pragma unroll
    for (int p = 0; p < 4; ++p) {
      const int i = (p << 8) + tid;
      int row = m0 + (i >> 3);
      if (row > MROWS - 1) row = MROWS - 1;  // discarded rows only
      gload_lds16(Zm + ((size_t)row << 11) + (kb << 6) + ((i & 7) << 3), &As[i << 3]);
    }
    const __hip_bfloat16* wb = W2t + ((size_t)((n0 >> 7) * 32 + kb) << 13);
#pragma unroll
    for (int p = 0; p < 4; ++p) {
      const int i = (p << 8) + tid;
      gload_lds16(wb + (i << 3), &Bs[i << 3]);
    }
    __syncthreads();
#pragma unroll
    for (int kk = 0; kk < 2; ++kk) {
      const int ko = (kk << 5) + ((lane >> 4) << 3);
      short8 av[4], bv[4];
#pragma unroll
      for (int m = 0; m < 4; ++m) {
        const int r = (wr << 6) + (m << 4) + (lane & 15);
        av[m] = *(const short8*)&As[(r << 6) + (ko ^ ((r & 7) << 3))];
      }
#pragma unroll
      for (int n = 0; n < 4; ++n) {
        const int br = (wc << 6) + (n << 4) + (lane & 15);
        bv[n] = *(const short8*)&Bs[(br << 6) + (ko ^ ((br & 7) << 3))];
      }
#pragma unroll
      for (int m = 0; m < 4; ++m)
#pragma unroll
        for (int n = 0; n < 4; ++n)
          acc[m][n] = __builtin_amdgcn_mfma_f32_16x16x32_bf16(av[m], bv[n], acc[m][n], 0, 0, 0);
    }
    __syncthreads();
  }

#pragma unroll
  for (int n = 0; n < 4; ++n) {
    const int col = n0 + (wc << 6) + (n << 4) + (lane & 15);
    const float b2v = b2[col];
#pragma unroll
    for (int m = 0; m < 4; ++m) {
      const int rbase = m0 + (wr << 6) + (m << 4) + ((lane >> 4) << 2);
#pragma unroll
      for (int r = 0; r < 4; ++r) {
        const int row = rbase + r;
        if (row < MROWS) Out[(size_t)row * NC + col] = acc[m][n][r] + b2v;
      }
    }
  }
}

// ---------------------------------------------------------------------------
extern "C" void kernel_launch(void* const* d_in, const int* in_sizes, int n_in,
                              void* d_out, int out_size, void* d_ws, size_t ws_size,
                              hipStream_t stream) {
  const float* x = (const float*)d_in[0];
  const float* Wl = (const float*)d_in[1];
  const float* bl = (const float*)d_in[2];
  const float* bias = (const float*)d_in[3];
  const float* Wc = (const float*)d_in[4];
  const float* bc = (const float*)d_in[5];
  const float* W2 = (const float*)d_in[6];
  const float* b2 = (const float*)d_in[7];
  float* out = (float*)d_out;

  char* ws = (char*)d_ws;
  __hip_bfloat16* Wt = (__hip_bfloat16*)(ws);                    // 31*8*2048*64*2 = 65,011,712
  __hip_bfloat16* Y = (__hip_bfloat16*)(ws + 65011712);          // 8*1024*512*2   =  8,388,608
  __hip_bfloat16* W2t = (__hip_bfloat16*)(ws + 73400320);        // 32*512*64*2    =  2,097,152
  __hip_bfloat16* Z = (__hip_bfloat16*)(ws + 75497472);          // 8*994*2048*2   = 32,571,392

  hipLaunchKernelGGL(prep_wc, dim3(2048), dim3(256), 0, stream, Wc, Wt);
  hipLaunchKernelGGL(prep_w2, dim3(4096), dim3(256), 0, stream, W2, W2t);
  hipLaunchKernelGGL(dynconv, dim3(NT / TG, NB), dim3(256), 0, stream, x, Wl, bl, bias, Y);
  hipLaunchKernelGGL(conv_gemm, dim3(NHID / 128, 8, NB), dim3(256), 0, stream, Y, Wt, bc, Z);
  hipLaunchKernelGGL(out_gemm, dim3(NC / 128, (MROWS + 127) / 128), dim3(256), 0, stream,
                     Z, W2t, b2, out);
}

// Round 4
// 707.460 us; speedup vs baseline: 1.6691x; 1.0712x over previous
//
#include <hip/hip_runtime.h>
#include <hip/hip_bf16.h>

typedef __attribute__((ext_vector_type(8))) short short8;
typedef __attribute__((ext_vector_type(4))) float f32x4;

#define NB 8
#define NT 1024
#define NC 512
#define NHID 2048
#define NK 31
#define NH 4
#define NTP 994            // NT - NK + 1
#define MROWS (NB * NTP)   // 7952
#define TG 4               // t's per dynconv block

__device__ __forceinline__ void gload_lds16(const void* g, void* l) {
  __builtin_amdgcn_global_load_lds(
      (const __attribute__((address_space(1))) void*)g,
      (__attribute__((address_space(3))) void*)l, 16, 0, 0);
}

// ---------------------------------------------------------------------------
// prep_wc: Wc (O=2048, C=512, K=31) fp32 -> Wt tiles [obig][cb][k][or][ci']
//   tile = 256 o-rows x 64 ci, ci' = ci ^ ((or&7)<<3)  (T2 swizzle baked in)
//   flat index: ((obig*8 + cb)*31 + k)*16384 + or*64 + ci'
// block: (o-tile of 8 rows, cb of 64 channels, all 31 k). grid = 2048
// ---------------------------------------------------------------------------
__global__ __launch_bounds__(256) void prep_wc(const float* __restrict__ Wc,
                                               __hip_bfloat16* __restrict__ Wt) {
  const int blk = blockIdx.x;
  const int cb = blk & 7;
  const int o0 = (blk >> 3) << 3;  // 8 o's per block
  const int c0 = cb << 6;
  const int obig = o0 >> 8;
  const int orb = o0 & 255;        // row base within 256-tile (mult of 8)
  __shared__ float lds[8 * 64 * NK];  // [ol][cl][k]  63.5KB
  for (int ol = 0; ol < 8; ++ol) {
    const float* src = Wc + ((size_t)(o0 + ol) * NC + c0) * NK;
    for (int i = threadIdx.x; i < 64 * NK; i += 256) lds[ol * (64 * NK) + i] = src[i];
  }
  __syncthreads();
  for (int i = threadIdx.x; i < NK * 8 * 64; i += 256) {
    const int k = i >> 9;          // /512
    const int rem = i & 511;
    const int ol = rem >> 6;
    const int ci = rem & 63;
    Wt[((size_t)((obig * 8 + cb) * NK + k) << 14) + ((orb + ol) << 6) + (ci ^ (ol << 3))] =
        __float2bfloat16(lds[ol * (64 * NK) + ci * NK + k]);
  }
}

// ---------------------------------------------------------------------------
// prep_w2: W2 (C=512, HID=2048) fp32 -> W2t tiles [nb][kb][cr][oi']
//   tile = 128 c-rows x 64 oi, oi' = oi ^ ((cr&7)<<3)
//   flat: ((nb*32 + kb)*128 + (c&127))*64 + oi'
// ---------------------------------------------------------------------------
__global__ __launch_bounds__(256) void prep_w2(const float* __restrict__ W2,
                                               __hip_bfloat16* __restrict__ W2t) {
  const int i = blockIdx.x * 256 + threadIdx.x;  // over 32*512*64 = 1048576
  if (i < 32 * 512 * 64) {
    const int oi = i & 63;
    const int c = (i >> 6) & 511;
    const int kb = i >> 15;
    const size_t dst = ((size_t)(((c >> 7) * 32 + kb) * 128 + (c & 127)) << 6) +
                       (oi ^ ((c & 7) << 3));
    W2t[dst] = __float2bfloat16(W2[(size_t)c * NHID + (kb << 6) + oi]);
  }
}

// ---------------------------------------------------------------------------
// dynconv: 4 t's per block. y[b,t,c] = sum_j w[h,j]*x[b,t+j-15,c] + bias[c]
// Y stored bf16 (B,T,C) with per-row swizzle: within each 64-ch block,
//   c' = c ^ ((t&7)<<3)   (so conv_gemm's LDS copy is conflict-free)
// ---------------------------------------------------------------------------
__global__ __launch_bounds__(256) void dynconv(const float* __restrict__ x,
                                               const float* __restrict__ Wl,
                                               const float* __restrict__ bl,
                                               const float* __restrict__ bias,
                                               __hip_bfloat16* __restrict__ Y) {
  const int t0 = blockIdx.x * TG;
  const int b = blockIdx.y;
  const int tid = threadIdx.x, lane = tid & 63, w = tid >> 6;
  __shared__ float xt[TG][NC];
  __shared__ float lg[TG][NH * NK];
  __shared__ float wsm[TG][NH][NK];

  for (int i = tid; i < TG * NC; i += 256) {
    const int tg = i >> 9, c = i & 511;
    xt[tg][c] = x[((size_t)b * NT + t0 + tg) * NC + c];
  }
  __syncthreads();

  // logits: wave w handles ids w, w+4, ... (124 = 4 waves * 31)
  for (int i = 0; i < 31; ++i) {
    const int id = (i << 2) | w;  // 0..123
    const float* wrow = Wl + (size_t)id * NC + (lane << 3);
    float wv[8];
#pragma unroll
    for (int u = 0; u < 8; ++u) wv[u] = wrow[u];
    const float blv = bl[id];
#pragma unroll
    for (int tg = 0; tg < TG; ++tg) {
      float s = 0.f;
#pragma unroll
      for (int u = 0; u < 8; ++u) s += xt[tg][(lane << 3) + u] * wv[u];
#pragma unroll
      for (int off = 32; off; off >>= 1) s += __shfl_xor(s, off);
      if (lane == 0) lg[tg][id] = s + blv;
    }
  }
  __syncthreads();

  if (tid < TG * NH) {  // 16 threads: (tg,h)
    const int tg = tid >> 2, h = tid & 3;
    const int t = t0 + tg;
    int jlo = 15 - t; if (jlo < 0) jlo = 0;
    int jhi = 1038 - t; if (jhi > 30) jhi = 30;
    float mx = -1e30f;
    for (int j = jlo; j <= jhi; ++j) mx = fmaxf(mx, lg[tg][h * NK + j]);
    float ssum = 0.f;
    for (int j = 0; j < NK; ++j) {
      const float e = (j >= jlo && j <= jhi) ? __expf(lg[tg][h * NK + j] - mx) : 0.f;
      wsm[tg][h][j] = e;
      ssum += e;
    }
    const float inv = 1.f / ssum;
    for (int j = 0; j < NK; ++j) wsm[tg][h][j] *= inv;
  }
  __syncthreads();

  // gather: thread owns float2 channel pair (c = 2*tid, 2*tid+1)
  const int c = tid << 1;
  const int h = c >> 7;
  const float2* x2 = (const float2*)x;
  const float bias0 = bias[c], bias1 = bias[c + 1];
#pragma unroll
  for (int tg = 0; tg < TG; ++tg) {
    const int t = t0 + tg;
    float a0 = 0.f, a1 = 0.f;
#pragma unroll
    for (int j = 0; j < NK; ++j) {
      int pos = t + j - 15;
      pos = pos < 0 ? 0 : (pos > NT - 1 ? NT - 1 : pos);  // OOB taps have w==0
      const float wgt = wsm[tg][h][j];
      const float2 v = x2[(((size_t)b * NT + pos) << 8) + tid];
      a0 += wgt * v.x;
      a1 += wgt * v.y;
    }
    const int cs = (c & ~63) | ((c & 63) ^ ((t & 7) << 3));  // swizzled (bit0 preserved)
    __hip_bfloat162 hv;
    hv.x = __float2bfloat16(a0 + bias0);
    hv.y = __float2bfloat16(a1 + bias1);
    *(__hip_bfloat162*)(Y + ((size_t)b * NT + t) * NC + cs) = hv;
  }
}

// ---------------------------------------------------------------------------
// conv_gemm: z[(b,t'),o] = sum_{k,c} Y[b,t'+k,c]*Wc[o,c,k]; +bc; selu -> Z bf16
// 256x256 tile, 8 waves (2Mx4N, per-wave 128x64). Counted-vmcnt schedule:
//   step s body: issue B(s+1) -> vmcnt(4) [B(s) landed] -> barrier ->
//   frags+MFMA (setprio) -> barrier [readers done before B(s+2) overwrites].
// B prefetch stays in flight ACROSS barriers (never vmcnt(0) in main loop).
// Ys (A-panel, 288 rows) hoisted per-cb, single-buffered; refill after
// barrier#2 of each cb's last step, covered by next step's vmcnt(4)
// (FIFO retire order: B(s+1), Ys, B(s+2)).
// Z written swizzled, key = flattened row (b*NTP+tp)&7 (matches out_gemm).
// ---------------------------------------------------------------------------
__global__ __launch_bounds__(512, 2) void conv_gemm(const __hip_bfloat16* __restrict__ Y,
                                                    const __hip_bfloat16* __restrict__ Wt,
                                                    const float* __restrict__ bc,
                                                    __hip_bfloat16* __restrict__ Z) {
  const int o0 = blockIdx.x << 8;   // 8 col-tiles
  const int t0 = blockIdx.y << 8;   // 4 row-tiles per batch
  const int b = blockIdx.z;
  __shared__ __align__(16) __hip_bfloat16 Ys[288 * 64];      // 36,864 B
  __shared__ __align__(16) __hip_bfloat16 Bs[2][256 * 64];   // 2x32,768 B  (total 102,400)
  const int tid = threadIdx.x;
  const int lane = tid & 63, wid = tid >> 6;
  const int wr = wid >> 2, wcid = wid & 3;
  const int obig = o0 >> 8;

  f32x4 acc[8][4] = {};

  auto stageY = [&](int cb_) {
    const int c0 = cb_ << 6;
#pragma unroll
    for (int p = 0; p < 5; ++p) {
      const int i = (p << 9) + tid;          // 2304 chunks of 16B = 288 rows
      if (i < 2304) {                        // wave-uniform (2304 = 36*64)
        int grow = t0 + (i >> 3);
        if (grow > NT - 1) grow = NT - 1;    // feeds only discarded output rows
        gload_lds16(Y + (((size_t)b * NT + grow) << 9) + c0 + ((i & 7) << 3),
                    &Ys[i << 3]);
      }
    }
  };
  auto stageB = [&](int bufi, int s_) {      // s_ = cb*31 + k
    const __hip_bfloat16* wb = Wt + (((size_t)(obig * 248 + s_)) << 14);
#pragma unroll
    for (int p = 0; p < 4; ++p) {
      const int i = (p << 9) + tid;          // 2048 chunks of 16B
      gload_lds16(wb + (i << 3), &Bs[bufi][i << 3]);
    }
  };

  // prologue: Ys(0) + B(0) in flight; body's vmcnt(4) covers both.
  stageY(0);
  stageB(0, 0);

  int buf = 0;
  for (int cb = 0; cb < 8; ++cb) {
    for (int k = 0; k < NK; ++k) {
      const int s = cb * 31 + k;
      if (s < 247) {
        stageB(buf ^ 1, s + 1);
        asm volatile("s_waitcnt vmcnt(4)" ::: "memory");   // B(s)+Ys landed; B(s+1) in flight
      } else {
        asm volatile("s_waitcnt vmcnt(0)" ::: "memory");   // last step: drain
      }
      __builtin_amdgcn_sched_barrier(0);
      __builtin_amdgcn_s_barrier();          // all waves' B(s) visible
      __builtin_amdgcn_sched_barrier(0);

      __builtin_amdgcn_s_setprio(1);
#pragma unroll
      for (int kk = 0; kk < 2; ++kk) {
        const int ko = (kk << 5) + ((lane >> 4) << 3);
        short8 av[8], bv[4];
#pragma unroll
        for (int m = 0; m < 8; ++m) {
          const int r2 = (wr << 7) + (m << 4) + (lane & 15) + k;
          av[m] = *(const short8*)&Ys[(r2 << 6) + (ko ^ ((r2 & 7) << 3))];
        }
#pragma unroll
        for (int n = 0; n < 4; ++n) {
          const int br = (wcid << 6) + (n << 4) + (lane & 15);
          bv[n] = *(const short8*)&Bs[buf][(br << 6) + (ko ^ ((br & 7) << 3))];
        }
#pragma unroll
        for (int m = 0; m < 8; ++m)
#pragma unroll
          for (int n = 0; n < 4; ++n)
            acc[m][n] = __builtin_amdgcn_mfma_f32_16x16x32_bf16(av[m], bv[n], acc[m][n], 0, 0, 0);
      }
      __builtin_amdgcn_s_setprio(0);

      __builtin_amdgcn_sched_barrier(0);
      __builtin_amdgcn_s_barrier();          // readers done before B(s+2) overwrite
      __builtin_amdgcn_sched_barrier(0);
      buf ^= 1;
    }
    if (cb < 7) stageY(cb + 1);  // Ys reads all retired (lgkm drained pre-MFMA + barrier)
  }

  const float kS = 1.0507009873554805f;
  const float kAS = 1.7580993408473766f;  // scale*alpha
#pragma unroll
  for (int n = 0; n < 4; ++n) {
    const int col = o0 + (wcid << 6) + (n << 4) + (lane & 15);
    const float bcv = bc[col];
#pragma unroll
    for (int m = 0; m < 8; ++m) {
      const int rbase = (wr << 7) + (m << 4) + ((lane >> 4) << 2);
#pragma unroll
      for (int r = 0; r < 4; ++r) {
        const int tp = t0 + rbase + r;
        if (tp < NTP) {
          const float v = acc[m][n][r] + bcv;
          const float s = v > 0.f ? kS * v : kAS * (__expf(v) - 1.f);
          const size_t grow = (size_t)b * NTP + tp;   // flattened row
          const int cs = (col & ~63) | ((col & 63) ^ (((int)(grow & 7)) << 3));
          Z[grow * NHID + cs] = __float2bfloat16(s);
        }
      }
    }
  }
}

// ---------------------------------------------------------------------------
// out_gemm: Out[row,c] = sum_o Z[row,o]*W2[c,o] + b2[c]  (fp32), M=7952,N=512,K=2048
// Z and W2t are pre-swizzled (Z key = flattened row&7); reads XOR-swizzled.
// ---------------------------------------------------------------------------
__global__ __launch_bounds__(256) void out_gemm(const __hip_bfloat16* __restrict__ Zm,
                                                const __hip_bfloat16* __restrict__ W2t,
                                                const float* __restrict__ b2,
                                                float* __restrict__ Out) {
  const int n0 = blockIdx.x << 7;
  const int m0 = blockIdx.y << 7;
  __shared__ __align__(16) __hip_bfloat16 As[128 * 64];
  __shared__ __align__(16) __hip_bfloat16 Bs[128 * 64];
  const int tid = threadIdx.x;
  const int lane = tid & 63, wid = tid >> 6;
  const int wr = wid >> 1, wc = wid & 1;

  f32x4 acc[4][4] = {};

  for (int kb = 0; kb < 32; ++kb) {
#pragma unroll
    for (int p = 0; p < 4; ++p) {
      const int i = (p << 8) + tid;
      int row = m0 + (i >> 3);
      if (row > MROWS - 1) row = MROWS - 1;  // discarded rows only
      gload_lds16(Zm + ((size_t)row << 11) + (kb << 6) + ((i & 7) << 3), &As[i << 3]);
    }
    const __hip_bfloat16* wb = W2t + ((size_t)((n0 >> 7) * 32 + kb) << 13);
#pragma unroll
    for (int p = 0; p < 4; ++p) {
      const int i = (p << 8) + tid;
      gload_lds16(wb + (i << 3), &Bs[i << 3]);
    }
    __syncthreads();
#pragma unroll
    for (int kk = 0; kk < 2; ++kk) {
      const int ko = (kk << 5) + ((lane >> 4) << 3);
      short8 av[4], bv[4];
#pragma unroll
      for (int m = 0; m < 4; ++m) {
        const int r = (wr << 6) + (m << 4) + (lane & 15);
        av[m] = *(const short8*)&As[(r << 6) + (ko ^ ((r & 7) << 3))];
      }
#pragma unroll
      for (int n = 0; n < 4; ++n) {
        const int br = (wc << 6) + (n << 4) + (lane & 15);
        bv[n] = *(const short8*)&Bs[(br << 6) + (ko ^ ((br & 7) << 3))];
      }
#pragma unroll
      for (int m = 0; m < 4; ++m)
#pragma unroll
        for (int n = 0; n < 4; ++n)
          acc[m][n] = __builtin_amdgcn_mfma_f32_16x16x32_bf16(av[m], bv[n], acc[m][n], 0, 0, 0);
    }
    __syncthreads();
  }

#pragma unroll
  for (int n = 0; n < 4; ++n) {
    const int col = n0 + (wc << 6) + (n << 4) + (lane & 15);
    const float b2v = b2[col];
#pragma unroll
    for (int m = 0; m < 4; ++m) {
      const int rbase = m0 + (wr << 6) + (m << 4) + ((lane >> 4) << 2);
#pragma unroll
      for (int r = 0; r < 4; ++r) {
        const int row = rbase + r;
        if (row < MROWS) Out[(size_t)row * NC + col] = acc[m][n][r] + b2v;
      }
    }
  }
}

// ---------------------------------------------------------------------------
extern "C" void kernel_launch(void* const* d_in, const int* in_sizes, int n_in,
                              void* d_out, int out_size, void* d_ws, size_t ws_size,
                              hipStream_t stream) {
  const float* x = (const float*)d_in[0];
  const float* Wl = (const float*)d_in[1];
  const float* bl = (const float*)d_in[2];
  const float* bias = (const float*)d_in[3];
  const float* Wc = (const float*)d_in[4];
  const float* bc = (const float*)d_in[5];
  const float* W2 = (const float*)d_in[6];
  const float* b2 = (const float*)d_in[7];
  float* out = (float*)d_out;

  char* ws = (char*)d_ws;
  __hip_bfloat16* Wt = (__hip_bfloat16*)(ws);                    // 31*8*2048*64*2 = 65,011,712
  __hip_bfloat16* Y = (__hip_bfloat16*)(ws + 65011712);          // 8*1024*512*2   =  8,388,608
  __hip_bfloat16* W2t = (__hip_bfloat16*)(ws + 73400320);        // 32*512*64*2    =  2,097,152
  __hip_bfloat16* Z = (__hip_bfloat16*)(ws + 75497472);          // 8*994*2048*2   = 32,571,392

  hipLaunchKernelGGL(prep_wc, dim3(2048), dim3(256), 0, stream, Wc, Wt);
  hipLaunchKernelGGL(prep_w2, dim3(4096), dim3(256), 0, stream, W2, W2t);
  hipLaunchKernelGGL(dynconv, dim3(NT / TG, NB), dim3(256), 0, stream, x, Wl, bl, bias, Y);
  hipLaunchKernelGGL(conv_gemm, dim3(NHID / 256, 4, NB), dim3(512), 0, stream, Y, Wt, bc, Z);
  hipLaunchKernelGGL(out_gemm, dim3(NC / 128, (MROWS + 127) / 128), dim3(256), 0, stream,
                     Z, W2t, b2, out);
}